// Round 19
// baseline (778.052 us; speedup 1.0000x reference)
//
#include <hip/hip_runtime.h>
#include <hip/hip_bf16.h>

typedef _Float16 f16;
typedef f16   f16x8 __attribute__((ext_vector_type(8)));
typedef float f32x4 __attribute__((ext_vector_type(4)));

#define HW 36864      /* 192*192 */
#define TS 9437184    /* 256*36864 : per-plane per-batch elements */

// async global->LDS, 16B per lane, LDS dest = wave-uniform base + lane*16
__device__ __forceinline__ void gload16(const void* g, void* lds) {
  __builtin_amdgcn_global_load_lds(
      (const __attribute__((address_space(1))) unsigned int*)g,
      (__attribute__((address_space(3))) unsigned int*)lds, 16, 0, 0);
}

// ---------------------------------------------------------------------------
// Pre-kernel: W (fp32 256x256) -> 3 fp16 planes: Wq, Wk, Wv
// ---------------------------------------------------------------------------
__global__ __launch_bounds__(256) void convert_w_kernel(
    const float* __restrict__ wq, const float* __restrict__ wk,
    const float* __restrict__ wv, f16* __restrict__ wp) {
  int i = blockIdx.x * 256 + threadIdx.x;  // 0 .. 65535
  wp[i]             = (f16)wq[i];
  wp[65536 + i]     = (f16)wk[i];
  wp[2 * 65536 + i] = (f16)wv[i];
}

// ---------------------------------------------------------------------------
// Stage 1: 1x1 conv GEMM  out[o,n] = sum_i W[o,i] x[i,n] + b[o]
// v9 = R13 machinery + T4 counted-vmcnt depth-3 pipeline.
// R13's __syncthreads drained vmcnt(0) every tile -> the prefetch it just
// issued was flushed at each barrier (CU ~70% idle: Mfma 15 + VALU 15).
// Here: half-K tiles [i=128][n=64] fp32 = 32KB x 3 buffers (96KB, 1 blk/CU);
// per half-tile: ISSUE(ht+2) ; COMPUTE(ht) ; s_waitcnt vmcnt(4) [ht+1 done,
// ht+2's 4 loads RIDE THROUGH the barrier] ; raw s_barrier. Acc persists
// across the 2 halves of each n-chunk; epilogue every 2nd half.
// Safety: per-wave vmcnt(4)+barrier => all waves' ht+1 loads complete;
// buf[(ht+2)%3] was last read before the PREVIOUS barrier => no DMA race.
// Swizzle identical to R13 (per-half i_loc): element (i_loc,n) at word
// i_loc*64 + (n ^ 8*((i_loc>>3)&3)); read col nc^(8*lg) -> 2 lanes/bank.
// sched_barrier(0) fencing per rule #18 (compiler must not hoist ds_reads
// past the inline-asm waitcnt / raw barrier).
// 512 thr, 8 waves (foq=wv>>1 x fnp=wv&1), grid (b,t) x 32 strips.
// ---------------------------------------------------------------------------
__global__ __launch_bounds__(512) void conv1x1_kernel(
    const float* __restrict__ xq, const float* __restrict__ xk, const float* __restrict__ xv,
    const f16* __restrict__ wp,
    const float* __restrict__ bq, const float* __restrict__ bk, const float* __restrict__ bv,
    f16* __restrict__ qkv) {
  const int bid   = blockIdx.x;
  const int bt    = bid >> 5;
  const int strip = bid & 31;        // 0..31, 18 n-chunks of 64 cols
  const int b     = bt / 3;
  const int t     = bt % 3;
  const float* __restrict__ in   = ((t == 0) ? xq : (t == 1 ? xk : xv)) + (size_t)b * TS;
  const float* __restrict__ bias = (t == 0) ? bq : (t == 1 ? bk : bv);
  const f16* __restrict__ W = wp + t * 65536;
  f16* __restrict__ outp    = qkv + (size_t)(b * 3 + t) * TS;

  const int tid = threadIdx.x;
  const int l   = tid & 63;
  const int wv  = tid >> 6;          // 0..7
  const int lr  = l & 15, lg = l >> 4;

  __shared__ __align__(16) float Xbuf[3][8192];   // 3 x 32KB fp32 [i=128][n=64]

  const int fnp = wv & 1;            // fn pair: {2*fnp, 2*fnp+1}
  const int foq = wv >> 1;           // fo quad: {4*foq .. 4*foq+3}

  float bz[4][4];
#pragma unroll
  for (int ff = 0; ff < 4; ++ff)
#pragma unroll
    for (int r = 0; r < 4; ++r) bz[ff][r] = bias[(foq * 4 + ff) * 16 + lg * 4 + r];

  // half-tile ht (0..35): n-chunk = ht>>1, i-half = ht&1. 32 jobs x 1KB.
  auto ISSUE = [&](int ht) {
    const int bufi = ht % 3;
    const int n0 = (strip * 18 + (ht >> 1)) * 64;
    const int ib = (ht & 1) << 7;    // +128 rows for odd halves
#pragma unroll
    for (int jj = 0; jj < 4; ++jj) {
      const int m    = wv * 4 + jj;                       // 0..31
      const int iloc = m * 4 + (l >> 4);                  // 0..127
      const int col  = 4 * ((l & 15) ^ (((m >> 1) & 3) << 1));
      gload16(in + (size_t)(ib + iloc) * HW + n0 + col,
              (char*)&Xbuf[bufi][0] + m * 1024);
    }
  };

  ISSUE(0);
  ISSUE(1);
  asm volatile("s_waitcnt vmcnt(4)" ::: "memory");   // ht0 complete, ht1 flying
  __builtin_amdgcn_sched_barrier(0);
  __builtin_amdgcn_s_barrier();
  __builtin_amdgcn_sched_barrier(0);

  f32x4 acc[4][2];
#pragma unroll
  for (int ff = 0; ff < 4; ++ff)
#pragma unroll
    for (int e = 0; e < 2; ++e) acc[ff][e] = (f32x4){0.f, 0.f, 0.f, 0.f};

  for (int ht = 0; ht < 36; ++ht) {
    if (ht + 2 < 36) {
      ISSUE(ht + 2);                 // rides through the next barrier
      __builtin_amdgcn_sched_barrier(0);
    }

    const float* __restrict__ Xc = &Xbuf[ht % 3][0];
    const int ihw = (ht & 1) * 128;  // W k-offset for this half

#pragma unroll
    for (int ks = 0; ks < 4; ++ks) {
      f16x8 bx[2];
#pragma unroll
      for (int e = 0; e < 2; ++e) {
        const int nc = lr + 16 * (fnp * 2 + e);
        union { f16 h[8]; f16x8 v; } u;
#pragma unroll
        for (int j = 0; j < 8; ++j)
          u.h[j] = (f16)Xc[(ks * 32 + lg * 8 + j) * 64 + (nc ^ (8 * lg))];
        bx[e] = u.v;
      }
      f16x8 aw[4];
#pragma unroll
      for (int ff = 0; ff < 4; ++ff)
        aw[ff] = *(const f16x8*)(W + ((foq * 4 + ff) * 16 + lr) * 256 + ihw + ks * 32 + lg * 8);
#pragma unroll
      for (int ff = 0; ff < 4; ++ff)
#pragma unroll
        for (int e = 0; e < 2; ++e)
          acc[ff][e] = __builtin_amdgcn_mfma_f32_16x16x32_f16(aw[ff], bx[e], acc[ff][e], 0, 0, 0);
    }

    if (ht & 1) {
      // epilogue for n-chunk ht>>1: C layout col n = lane&15, row o = 4*lg+reg
      const int n0 = (strip * 18 + (ht >> 1)) * 64;
#pragma unroll
      for (int ff = 0; ff < 4; ++ff) {
        const int orow = (foq * 4 + ff) * 16 + lg * 4;
#pragma unroll
        for (int e = 0; e < 2; ++e)
#pragma unroll
          for (int r = 0; r < 4; ++r)
            outp[(size_t)(orow + r) * HW + n0 + (fnp * 2 + e) * 16 + lr] =
                (f16)(acc[ff][e][r] + bz[ff][r]);
#pragma unroll
        for (int e = 0; e < 2; ++e) acc[ff][e] = (f32x4){0.f, 0.f, 0.f, 0.f};
      }
    }

    if (ht + 2 < 36) {
      asm volatile("s_waitcnt vmcnt(4)" ::: "memory");   // ht+1 done; ht+2 flying
    } else if (ht + 1 < 36) {
      asm volatile("s_waitcnt vmcnt(0)" ::: "memory");   // tail: drain last batch
    }
    if (ht + 1 < 36) {
      __builtin_amdgcn_sched_barrier(0);
      __builtin_amdgcn_s_barrier();
      __builtin_amdgcn_sched_barrier(0);
    }
  }
}

// ---------------------------------------------------------------------------
// Stage 2: attention, 768 threads (12 waves), one block per (b,c).
// blockIdx.x = b*256 + c. [K stage + issue aq/vp] B1 [QK^T, softmax, Pf]
// B2 [Vt write] B3 [PV]. LDS 153.6 KB -> 1 block/CU. (~175us — untouched.)
// ---------------------------------------------------------------------------
__global__ __launch_bounds__(768) void attn_kernel(
    const f16* __restrict__ qkv, float* __restrict__ outb) {
  const int c2  = blockIdx.x;
  const int b   = c2 >> 8;
  const int c   = c2 & 255;
  const int tid = threadIdx.x;
  const int l   = tid & 63;
  const int wv  = tid >> 6;          // 0..11  == q-tile index
  const int lr  = l & 15, lg = l >> 4;

  const f16* __restrict__ qb = qkv + (size_t)(b * 3) * TS;
  const f16* __restrict__ q = qb + (size_t)c * HW;
  const f16* __restrict__ k = qb + (size_t)TS + (size_t)c * HW;
  const f16* __restrict__ v = qb + 2 * (size_t)TS + (size_t)c * HW;
  float* __restrict__ outc = outb + (size_t)b * TS + (size_t)c * HW;

  __shared__ f16 KA[192][200];   // phase1: K [g][w]   phase2: V^T [w][g]
  __shared__ f16 Pf[192][200];   // normalized P [h][g]

  const int h0 = wv * 16;

  // ---- T14 issue-early: Q fragments (consumed in QK^T)
  f16x8 aq[6];
#pragma unroll
  for (int ks = 0; ks < 6; ++ks)
    aq[ks] = *(const f16x8*)(q + (h0 + lr) * 192 + ks * 32 + lg * 8);

  // ---- T14 issue-early: scattered V-gather into regs (written to LDS later)
  const int gA = (tid % 24) * 8, wA = (tid / 24) * 4;   // job A: all threads
  const int jB = tid + 768;                              // job B: tid < 384
  const int gB = (jB % 24) * 8, wB = (jB / 24) * 4;
  uint2 vpA[8], vpB[8];
#pragma unroll
  for (int j = 0; j < 8; ++j) vpA[j] = *(const uint2*)(v + (gA + j) * 192 + wA);
  if (tid < 384) {
#pragma unroll
    for (int j = 0; j < 8; ++j) vpB[j] = *(const uint2*)(v + (gB + j) * 192 + wB);
  }

  // ---- stage K -> KA (16B chunks, coalesced; 4608 = 768*6)
#pragma unroll
  for (int jj = 0; jj < 6; ++jj) {
    int id = tid + jj * 768;
    int g = id / 24, wo = id % 24;
    *(f16x8*)&KA[g][wo * 8] = *(const f16x8*)(k + g * 192 + wo * 8);
  }
  __syncthreads();                              // B1: K visible

  {
    f32x4 S[12];
#pragma unroll
    for (int fg = 0; fg < 12; ++fg) S[fg] = (f32x4){0.f, 0.f, 0.f, 0.f};
#pragma unroll
    for (int ks = 0; ks < 6; ++ks)
#pragma unroll
      for (int fg = 0; fg < 12; ++fg) {
        f16x8 bk_ = *(const f16x8*)&KA[16 * fg + lr][ks * 32 + lg * 8];
        S[fg] = __builtin_amdgcn_mfma_f32_16x16x32_f16(aq[ks], bk_, S[fg], 0, 0, 0);
      }

    // exact softmax per row (row = 4*lg + r; 16 lanes lr hold g-chunks),
    // normalize, store to Pf in [h][g] layout (C-layout-native scatter).
#pragma unroll
    for (int r = 0; r < 4; ++r) {
      float m = S[0][r];
#pragma unroll
      for (int fg = 1; fg < 12; ++fg) m = fmaxf(m, S[fg][r]);
      m = fmaxf(m, __shfl_xor(m, 1));
      m = fmaxf(m, __shfl_xor(m, 2));
      m = fmaxf(m, __shfl_xor(m, 4));
      m = fmaxf(m, __shfl_xor(m, 8));
      float s = 0.f;
#pragma unroll
      for (int fg = 0; fg < 12; ++fg) {
        float e = __expf(S[fg][r] - m);
        S[fg][r] = e;
        s += e;
      }
      s += __shfl_xor(s, 1);
      s += __shfl_xor(s, 2);
      s += __shfl_xor(s, 4);
      s += __shfl_xor(s, 8);
      float rs = 1.f / s;
#pragma unroll
      for (int fg = 0; fg < 12; ++fg)
        Pf[h0 + lg * 4 + r][16 * fg + lr] = (f16)(S[fg][r] * rs);
    }
  }
  __syncthreads();                              // B2: all KA reads done

  // ---- write V^T into KA from the preloaded regs (conflict-free b128 rows)
  {
#pragma unroll
    for (int qd = 0; qd < 4; ++qd) {
      union { unsigned short s[8]; f16x8 vec; } u;
#pragma unroll
      for (int j = 0; j < 8; ++j) u.s[j] = ((const unsigned short*)&vpA[j])[qd];
      *(f16x8*)&KA[wA + qd][gA] = u.vec;
    }
    if (tid < 384) {
#pragma unroll
      for (int qd = 0; qd < 4; ++qd) {
        union { unsigned short s[8]; f16x8 vec; } u;
#pragma unroll
        for (int j = 0; j < 8; ++j) u.s[j] = ((const unsigned short*)&vpB[j])[qd];
        *(f16x8*)&KA[wB + qd][gB] = u.vec;
      }
    }
  }
  __syncthreads();                              // B3: V^T visible

  {
    f32x4 O[12];
#pragma unroll
    for (int fn = 0; fn < 12; ++fn) O[fn] = (f32x4){0.f, 0.f, 0.f, 0.f};

#pragma unroll
    for (int ks = 0; ks < 6; ++ks) {
      f16x8 pa = *(const f16x8*)&Pf[h0 + lr][ks * 32 + lg * 8];  // A: row h, k = g
#pragma unroll
      for (int fn = 0; fn < 12; ++fn) {
        f16x8 bv_ = *(const f16x8*)&KA[16 * fn + lr][ks * 32 + lg * 8];  // B: col w, k = g
        O[fn] = __builtin_amdgcn_mfma_f32_16x16x32_f16(pa, bv_, O[fn], 0, 0, 0);
      }
    }

#pragma unroll
    for (int fn = 0; fn < 12; ++fn)
#pragma unroll
      for (int r = 0; r < 4; ++r)
        outc[(size_t)(h0 + lg * 4 + r) * 192 + 16 * fn + lr] = O[fn][r];
  }
}

// ---------------------------------------------------------------------------
extern "C" void kernel_launch(void* const* d_in, const int* in_sizes, int n_in,
                              void* d_out, int out_size, void* d_ws, size_t ws_size,
                              hipStream_t stream) {
  const float* query = (const float*)d_in[0];
  const float* key_  = (const float*)d_in[1];
  const float* value = (const float*)d_in[2];
  const float* Wq    = (const float*)d_in[3];
  const float* bq    = (const float*)d_in[4];
  const float* Wk    = (const float*)d_in[5];
  const float* bk    = (const float*)d_in[6];
  const float* Wv    = (const float*)d_in[7];
  const float* bv    = (const float*)d_in[8];
  float* out = (float*)d_out;

  f16* wp  = (f16*)d_ws;                        // 3*65536 fp16 = 384 KB
  f16* qkv = (f16*)((char*)d_ws + 524288);

  convert_w_kernel<<<256, 256, 0, stream>>>(Wq, Wk, Wv, wp);

  const size_t need_fused = 524288 + (size_t)8 * 3 * TS * 2;  // ~453.5 MB
  if (ws_size >= need_fused) {
    // Fused: all 8 batches; conv grid 768 blocks (3 exact CU-rounds).
    conv1x1_kernel<<<32 * 3 * 8, 512, 0, stream>>>(
        query, key_, value, wp, bq, bk, bv, qkv);
    attn_kernel<<<2048, 768, 0, stream>>>(qkv, out);
  } else {
    // Fallback: per-batch loop.
    for (int b = 0; b < 8; ++b) {
      const size_t off = (size_t)b * TS;
      conv1x1_kernel<<<32 * 3, 512, 0, stream>>>(
          query + off, key_ + off, value + off, wp, bq, bk, bv, qkv);
      attn_kernel<<<256, 768, 0, stream>>>(qkv, out + off);
    }
  }
}

// Round 20
// 501.270 us; speedup vs baseline: 1.5522x; 1.5522x over previous
//
#include <hip/hip_runtime.h>
#include <hip/hip_bf16.h>

typedef _Float16 f16;
typedef f16   f16x8 __attribute__((ext_vector_type(8)));
typedef float f32x4 __attribute__((ext_vector_type(4)));

#define HW 36864      /* 192*192 */
#define TS 9437184    /* 256*36864 : per-plane per-batch elements */

// async global->LDS, 16B per lane, LDS dest = wave-uniform base + lane*16
__device__ __forceinline__ void gload16(const void* g, void* lds) {
  __builtin_amdgcn_global_load_lds(
      (const __attribute__((address_space(1))) unsigned int*)g,
      (__attribute__((address_space(3))) unsigned int*)lds, 16, 0, 0);
}

// ---------------------------------------------------------------------------
// Pre-kernel: W (fp32 256x256) -> 3 fp16 planes: Wq, Wk, Wv
// ---------------------------------------------------------------------------
__global__ __launch_bounds__(256) void convert_w_kernel(
    const float* __restrict__ wq, const float* __restrict__ wk,
    const float* __restrict__ wv, f16* __restrict__ wp) {
  int i = blockIdx.x * 256 + threadIdx.x;  // 0 .. 65535
  wp[i]             = (f16)wq[i];
  wp[65536 + i]     = (f16)wk[i];
  wp[2 * 65536 + i] = (f16)wv[i];
}

// ---------------------------------------------------------------------------
// Stage 1: 1x1 conv GEMM  out[o,n] = sum_i W[o,i] x[i,n] + b[o]
// == R13 VERBATIM — empirical optimum (319us, VGPR 128, zero spill). ==
// X staged as FP32 via global_load_lds (async, zero reg footprint),
// LDS-linear [i=256][n=64]; fp32->f16 at consume. 2-phase double buffer:
// ISSUE(t+1 -> buf^1); COMPUTE(buf); barrier; swap.
// Swizzle: element (i,n) at fp32 word i*64 + (n ^ 8*((i>>3)&3)); read col
// nc^(8*lg) -> 2 lanes/bank both sides.
// 8 waves: wave w = fo-quad (w>>1) x fn-pair (w&1); acc[4][2] = 32 regs.
// Failed alternatives (do not retry): register prefetch R12/R14/R16
// (allocator spill), 1024 thr R15 (VGPR=64 cap), 32-col tiles R18 (HBM
// write amplification), counted-vmcnt half-tiles R19 (2x barrier cost).
// 512 threads, LDS 128KB (1 blk/CU), grid (b,t) x 32 strips, 18 tiles each.
// ---------------------------------------------------------------------------
__global__ __launch_bounds__(512) void conv1x1_kernel(
    const float* __restrict__ xq, const float* __restrict__ xk, const float* __restrict__ xv,
    const f16* __restrict__ wp,
    const float* __restrict__ bq, const float* __restrict__ bk, const float* __restrict__ bv,
    f16* __restrict__ qkv) {
  const int bid   = blockIdx.x;
  const int bt    = bid >> 5;
  const int strip = bid & 31;        // 0..31, 18 tiles of 64 cols each
  const int b     = bt / 3;
  const int t     = bt % 3;
  const float* __restrict__ in   = ((t == 0) ? xq : (t == 1 ? xk : xv)) + (size_t)b * TS;
  const float* __restrict__ bias = (t == 0) ? bq : (t == 1 ? bk : bv);
  const f16* __restrict__ W = wp + t * 65536;
  f16* __restrict__ outp    = qkv + (size_t)(b * 3 + t) * TS;

  const int tid = threadIdx.x;
  const int l   = tid & 63;
  const int wv  = tid >> 6;          // 0..7
  const int lr  = l & 15, lg = l >> 4;

  __shared__ __align__(16) float Xbuf[2][16384];   // 2 x 64KB fp32 [i=256][n=64]

  const int fnp = wv & 1;            // fn pair: {2*fnp, 2*fnp+1}
  const int foq = wv >> 1;           // fo quad: {4*foq .. 4*foq+3}

  float bz[4][4];
#pragma unroll
  for (int ff = 0; ff < 4; ++ff)
#pragma unroll
    for (int r = 0; r < 4; ++r) bz[ff][r] = bias[(foq * 4 + ff) * 16 + lg * 4 + r];

  // stage: wave wv issues m = wv*8+jj; rows i0 = m*4 + (l>>4); 16B at
  // swizzled col 4*((l&15) ^ (((m>>1)&3)<<1)); LDS dst linear m*1024.
  auto ISSUE = [&](int tile, int bufi) {
    const int n0 = (strip * 18 + tile) * 64;
#pragma unroll
    for (int jj = 0; jj < 8; ++jj) {
      const int m   = wv * 8 + jj;
      const int i0  = m * 4 + (l >> 4);
      const int col = 4 * ((l & 15) ^ (((m >> 1) & 3) << 1));
      gload16(in + (size_t)i0 * HW + n0 + col, (char*)&Xbuf[bufi][0] + m * 1024);
    }
  };

  ISSUE(0, 0);
  __syncthreads();                   // drains vmcnt -> buf0 ready

  int cur = 0;
  for (int it = 0; it < 18; ++it) {
    if (it < 17) ISSUE(it + 1, cur ^ 1);   // async loads fly under compute

    const float* __restrict__ Xc = &Xbuf[cur][0];
    const int n0 = (strip * 18 + it) * 64;

    f32x4 acc[4][2];
#pragma unroll
    for (int ff = 0; ff < 4; ++ff)
#pragma unroll
      for (int e = 0; e < 2; ++e) acc[ff][e] = (f32x4){0.f, 0.f, 0.f, 0.f};

#pragma unroll
    for (int ks = 0; ks < 8; ++ks) {
      f16x8 bx[2];
#pragma unroll
      for (int e = 0; e < 2; ++e) {
        const int nc = lr + 16 * (fnp * 2 + e);
        union { f16 h[8]; f16x8 v; } u;
#pragma unroll
        for (int j = 0; j < 8; ++j)
          u.h[j] = (f16)Xc[(ks * 32 + lg * 8 + j) * 64 + (nc ^ (lg * 8))];
        bx[e] = u.v;
      }
      f16x8 aw[4];
#pragma unroll
      for (int ff = 0; ff < 4; ++ff)
        aw[ff] = *(const f16x8*)(W + ((foq * 4 + ff) * 16 + lr) * 256 + ks * 32 + lg * 8);
#pragma unroll
      for (int ff = 0; ff < 4; ++ff)
#pragma unroll
        for (int e = 0; e < 2; ++e)
          acc[ff][e] = __builtin_amdgcn_mfma_f32_16x16x32_f16(aw[ff], bx[e], acc[ff][e], 0, 0, 0);
    }

    // epilogue: C layout col n = lane&15, row o = 4*(lane>>4)+reg
#pragma unroll
    for (int ff = 0; ff < 4; ++ff) {
      const int orow = (foq * 4 + ff) * 16 + lg * 4;
#pragma unroll
      for (int e = 0; e < 2; ++e)
#pragma unroll
        for (int r = 0; r < 4; ++r)
          outp[(size_t)(orow + r) * HW + n0 + (fnp * 2 + e) * 16 + lr] =
              (f16)(acc[ff][e][r] + bz[ff][r]);
    }

    __syncthreads();                 // drains next-tile loads, guards buf reuse
    cur ^= 1;
  }
}

// ---------------------------------------------------------------------------
// Stage 2: attention, 768 threads (12 waves), one block per (b,c).
// blockIdx.x = b*256 + c. [K stage + issue aq/vp] B1 [QK^T, softmax, Pf]
// B2 [Vt write] B3 [PV]. LDS 153.6 KB -> 1 block/CU. (~175us — untouched.)
// ---------------------------------------------------------------------------
__global__ __launch_bounds__(768) void attn_kernel(
    const f16* __restrict__ qkv, float* __restrict__ outb) {
  const int c2  = blockIdx.x;
  const int b   = c2 >> 8;
  const int c   = c2 & 255;
  const int tid = threadIdx.x;
  const int l   = tid & 63;
  const int wv  = tid >> 6;          // 0..11  == q-tile index
  const int lr  = l & 15, lg = l >> 4;

  const f16* __restrict__ qb = qkv + (size_t)(b * 3) * TS;
  const f16* __restrict__ q = qb + (size_t)c * HW;
  const f16* __restrict__ k = qb + (size_t)TS + (size_t)c * HW;
  const f16* __restrict__ v = qb + 2 * (size_t)TS + (size_t)c * HW;
  float* __restrict__ outc = outb + (size_t)b * TS + (size_t)c * HW;

  __shared__ f16 KA[192][200];   // phase1: K [g][w]   phase2: V^T [w][g]
  __shared__ f16 Pf[192][200];   // normalized P [h][g]

  const int h0 = wv * 16;

  // ---- T14 issue-early: Q fragments (consumed in QK^T)
  f16x8 aq[6];
#pragma unroll
  for (int ks = 0; ks < 6; ++ks)
    aq[ks] = *(const f16x8*)(q + (h0 + lr) * 192 + ks * 32 + lg * 8);

  // ---- T14 issue-early: scattered V-gather into regs (written to LDS later)
  const int gA = (tid % 24) * 8, wA = (tid / 24) * 4;   // job A: all threads
  const int jB = tid + 768;                              // job B: tid < 384
  const int gB = (jB % 24) * 8, wB = (jB / 24) * 4;
  uint2 vpA[8], vpB[8];
#pragma unroll
  for (int j = 0; j < 8; ++j) vpA[j] = *(const uint2*)(v + (gA + j) * 192 + wA);
  if (tid < 384) {
#pragma unroll
    for (int j = 0; j < 8; ++j) vpB[j] = *(const uint2*)(v + (gB + j) * 192 + wB);
  }

  // ---- stage K -> KA (16B chunks, coalesced; 4608 = 768*6)
#pragma unroll
  for (int jj = 0; jj < 6; ++jj) {
    int id = tid + jj * 768;
    int g = id / 24, wo = id % 24;
    *(f16x8*)&KA[g][wo * 8] = *(const f16x8*)(k + g * 192 + wo * 8);
  }
  __syncthreads();                              // B1: K visible

  {
    f32x4 S[12];
#pragma unroll
    for (int fg = 0; fg < 12; ++fg) S[fg] = (f32x4){0.f, 0.f, 0.f, 0.f};
#pragma unroll
    for (int ks = 0; ks < 6; ++ks)
#pragma unroll
      for (int fg = 0; fg < 12; ++fg) {
        f16x8 bk_ = *(const f16x8*)&KA[16 * fg + lr][ks * 32 + lg * 8];
        S[fg] = __builtin_amdgcn_mfma_f32_16x16x32_f16(aq[ks], bk_, S[fg], 0, 0, 0);
      }

    // exact softmax per row (row = 4*lg + r; 16 lanes lr hold g-chunks),
    // normalize, store to Pf in [h][g] layout (C-layout-native scatter).
#pragma unroll
    for (int r = 0; r < 4; ++r) {
      float m = S[0][r];
#pragma unroll
      for (int fg = 1; fg < 12; ++fg) m = fmaxf(m, S[fg][r]);
      m = fmaxf(m, __shfl_xor(m, 1));
      m = fmaxf(m, __shfl_xor(m, 2));
      m = fmaxf(m, __shfl_xor(m, 4));
      m = fmaxf(m, __shfl_xor(m, 8));
      float s = 0.f;
#pragma unroll
      for (int fg = 0; fg < 12; ++fg) {
        float e = __expf(S[fg][r] - m);
        S[fg][r] = e;
        s += e;
      }
      s += __shfl_xor(s, 1);
      s += __shfl_xor(s, 2);
      s += __shfl_xor(s, 4);
      s += __shfl_xor(s, 8);
      float rs = 1.f / s;
#pragma unroll
      for (int fg = 0; fg < 12; ++fg)
        Pf[h0 + lg * 4 + r][16 * fg + lr] = (f16)(S[fg][r] * rs);
    }
  }
  __syncthreads();                              // B2: all KA reads done

  // ---- write V^T into KA from the preloaded regs (conflict-free b128 rows)
  {
#pragma unroll
    for (int qd = 0; qd < 4; ++qd) {
      union { unsigned short s[8]; f16x8 vec; } u;
#pragma unroll
      for (int j = 0; j < 8; ++j) u.s[j] = ((const unsigned short*)&vpA[j])[qd];
      *(f16x8*)&KA[wA + qd][gA] = u.vec;
    }
    if (tid < 384) {
#pragma unroll
      for (int qd = 0; qd < 4; ++qd) {
        union { unsigned short s[8]; f16x8 vec; } u;
#pragma unroll
        for (int j = 0; j < 8; ++j) u.s[j] = ((const unsigned short*)&vpB[j])[qd];
        *(f16x8*)&KA[wB + qd][gB] = u.vec;
      }
    }
  }
  __syncthreads();                              // B3: V^T visible

  {
    f32x4 O[12];
#pragma unroll
    for (int fn = 0; fn < 12; ++fn) O[fn] = (f32x4){0.f, 0.f, 0.f, 0.f};

#pragma unroll
    for (int ks = 0; ks < 6; ++ks) {
      f16x8 pa = *(const f16x8*)&Pf[h0 + lr][ks * 32 + lg * 8];  // A: row h, k = g
#pragma unroll
      for (int fn = 0; fn < 12; ++fn) {
        f16x8 bv_ = *(const f16x8*)&KA[16 * fn + lr][ks * 32 + lg * 8];  // B: col w, k = g
        O[fn] = __builtin_amdgcn_mfma_f32_16x16x32_f16(pa, bv_, O[fn], 0, 0, 0);
      }
    }

#pragma unroll
    for (int fn = 0; fn < 12; ++fn)
#pragma unroll
      for (int r = 0; r < 4; ++r)
        outc[(size_t)(h0 + lg * 4 + r) * 192 + 16 * fn + lr] = O[fn][r];
  }
}

// ---------------------------------------------------------------------------
extern "C" void kernel_launch(void* const* d_in, const int* in_sizes, int n_in,
                              void* d_out, int out_size, void* d_ws, size_t ws_size,
                              hipStream_t stream) {
  const float* query = (const float*)d_in[0];
  const float* key_  = (const float*)d_in[1];
  const float* value = (const float*)d_in[2];
  const float* Wq    = (const float*)d_in[3];
  const float* bq    = (const float*)d_in[4];
  const float* Wk    = (const float*)d_in[5];
  const float* bk    = (const float*)d_in[6];
  const float* Wv    = (const float*)d_in[7];
  const float* bv    = (const float*)d_in[8];
  float* out = (float*)d_out;

  f16* wp  = (f16*)d_ws;                        // 3*65536 fp16 = 384 KB
  f16* qkv = (f16*)((char*)d_ws + 524288);

  convert_w_kernel<<<256, 256, 0, stream>>>(Wq, Wk, Wv, wp);

  const size_t need_fused = 524288 + (size_t)8 * 3 * TS * 2;  // ~453.5 MB
  if (ws_size >= need_fused) {
    // Fused: all 8 batches; conv grid 768 blocks (3 exact CU-rounds).
    conv1x1_kernel<<<32 * 3 * 8, 512, 0, stream>>>(
        query, key_, value, wp, bq, bk, bv, qkv);
    attn_kernel<<<2048, 768, 0, stream>>>(qkv, out);
  } else {
    // Fallback: per-batch loop.
    for (int b = 0; b < 8; ++b) {
      const size_t off = (size_t)b * TS;
      conv1x1_kernel<<<32 * 3, 512, 0, stream>>>(
          query + off, key_ + off, value + off, wp, bq, bk, bv, qkv);
      attn_kernel<<<256, 768, 0, stream>>>(qkv, out + off);
    }
  }
}